// Round 9
// baseline (1336.715 us; speedup 1.0000x reference)
//
#include <hip/hip_runtime.h>

#define F_IN 1433
#define H1 200
#define H2 80
#define NC 7

typedef __bf16 bf16x8 __attribute__((ext_vector_type(8)));
typedef float f32x4 __attribute__((ext_vector_type(4)));
typedef int i32x2 __attribute__((ext_vector_type(2)));

__device__ __forceinline__ unsigned short bf16_bits(__bf16 h) {
    union { __bf16 h; unsigned short u; } c; c.h = h; return c.u;
}
__device__ __forceinline__ void split_bf16(float a, __bf16& hi, __bf16& lo) {
    hi = (__bf16)a;
    lo = (__bf16)(a - (float)hi);
}

struct AF { float v[8]; };

__device__ __forceinline__ void glds16(const void* g, void* l) {
    __builtin_amdgcn_global_load_lds(
        (const __attribute__((address_space(1))) unsigned int*)g,
        (__attribute__((address_space(3))) unsigned int*)l, 16, 0, 0);
}

// =================== split-bf16 MFMA GEMM, double-buffered LDS, 1 barrier/step ===================
// C[M][NREAL] = A[M][K] @ B[K][NREAL] (+bias). Bpre layout (shorts), per k-step s:
//   Bpre[s][hl][k8l][col][j]  (PER_STEP = 2*4*COLS*8 shorts, zero-padded)
// Block: 512 thr = 8 waves as WR x WC over a 128 x COLS tile.
// Loop: { stageB(s+1 -> buf^1) ISSUED FIRST; convert A; loadA(s+1); MFMA from buf;
//         __syncthreads (drains stage under-the-MFMAs); swap }  -- T3 2-phase recipe.
template <int K, int KSTEPS, int COLS, int WR, int WC, int MT, int NT, bool BIAS>
__global__ __launch_bounds__(512, 4)
void gemm_mfma_dbuf(const float* __restrict__ A, const unsigned short* __restrict__ Bpre,
                    const float* __restrict__ bias, float* __restrict__ C,
                    int M, int NREAL) {
    static_assert(WR * WC == 8, "8 waves");
    static_assert(WR * MT * 16 == 128, "rows");
    static_assert(WC * NT * 16 == COLS, "cols");
    constexpr int THREADS = 512;
    constexpr int PER_STEP = 2 * 4 * COLS * 8;   // shorts per k-step
    constexpr int CH = COLS * 8;                 // 16B chunks per k-step
    constexpr bool PART = (KSTEPS * 32 > K);

    __shared__ alignas(16) unsigned short Bs[2][PER_STEP];

    const int tid = threadIdx.x;
    const int wave = tid >> 6, lane = tid & 63;
    const int l15 = lane & 15, l4 = lane >> 4;
    const int wr = wave / WC, wc = wave % WC;
    const int row0 = blockIdx.x * 128 + wr * (MT * 16);
    const int colbase = wc * (NT * 16);

    f32x4 acc[MT][NT];
    #pragma unroll
    for (int m = 0; m < MT; ++m)
        #pragma unroll
        for (int n = 0; n < NT; ++n) acc[m][n] = (f32x4){0.f, 0.f, 0.f, 0.f};

    const float* arow[MT];
    #pragma unroll
    for (int m = 0; m < MT; ++m) {
        int r = row0 + m * 16 + l15;
        if (r >= M) r = M - 1;            // clamp; OOB rows masked at store
        arow[m] = A + (size_t)r * K;
    }

    auto loadA = [&](int s, AF* dst) {
        const int kb = s * 32 + l4 * 8;
        #pragma unroll
        for (int m = 0; m < MT; ++m) {
            const float* ap = arow[m] + kb;
            if (PART && s == KSTEPS - 1) {
                #pragma unroll
                for (int j = 0; j < 8; ++j) dst[m].v[j] = (kb + j < K) ? ap[j] : 0.f;
            } else {
                #pragma unroll
                for (int j = 0; j < 8; ++j) dst[m].v[j] = ap[j];
            }
        }
    };

    auto stageB = [&](int s, int b) {
        const unsigned short* src = Bpre + (size_t)s * PER_STEP;
        for (int c = tid; c < CH; c += THREADS)
            glds16(src + (size_t)c * 8, &Bs[b][c * 8]);
    };

    AF aCur[MT], aNxt[MT];
    stageB(0, 0);
    loadA(0, aCur);
    __syncthreads();                             // buf0 staged (vmcnt drained)

    int cb = 0;
    for (int s = 0; s < KSTEPS; ++s) {
        if (s + 1 < KSTEPS) stageB(s + 1, cb ^ 1);   // issue next-step loads FIRST
        bf16x8 aHi[MT], aLo[MT];
        #pragma unroll
        for (int m = 0; m < MT; ++m)
            #pragma unroll
            for (int j = 0; j < 8; ++j) {
                __bf16 hi, lo;
                split_bf16(aCur[m].v[j], hi, lo);
                aHi[m][j] = hi;
                aLo[m][j] = lo;
            }
        if (s + 1 < KSTEPS) loadA(s + 1, aNxt);      // A prefetch to registers

        const unsigned short* bsc = &Bs[cb][0];
        #pragma unroll
        for (int n = 0; n < NT; ++n) {
            const int colb = colbase + n * 16 + l15;
            bf16x8 bHi = *(const bf16x8*)&bsc[((0 + l4) * COLS + colb) * 8];
            bf16x8 bLo = *(const bf16x8*)&bsc[((4 + l4) * COLS + colb) * 8];
            #pragma unroll
            for (int m = 0; m < MT; ++m) {
                acc[m][n] = __builtin_amdgcn_mfma_f32_16x16x32_bf16(aHi[m], bHi, acc[m][n], 0, 0, 0);
                acc[m][n] = __builtin_amdgcn_mfma_f32_16x16x32_bf16(aLo[m], bHi, acc[m][n], 0, 0, 0);
                acc[m][n] = __builtin_amdgcn_mfma_f32_16x16x32_bf16(aHi[m], bLo, acc[m][n], 0, 0, 0);
            }
        }
        __syncthreads();    // stage(s+1) drained (hid under MFMAs); readers of buf cb done
        cb ^= 1;
        #pragma unroll
        for (int m = 0; m < MT; ++m) aCur[m] = aNxt[m];
    }

    // epilogue: C/D layout col=lane&15, row=(lane>>4)*4+reg
    #pragma unroll
    for (int m = 0; m < MT; ++m) {
        const int rbase = row0 + m * 16 + l4 * 4;
        #pragma unroll
        for (int n = 0; n < NT; ++n) {
            int col = colbase + n * 16 + l15;
            if (col >= NREAL) continue;
            float bv = BIAS ? bias[col] : 0.f;
            #pragma unroll
            for (int r = 0; r < 4; ++r) {
                int gr = rbase + r;
                if (gr < M) C[(size_t)gr * NREAL + col] = acc[m][n][r] + bv;
            }
        }
    }
}

// Convert W[K][NREAL] fp32 -> Bpre[s][hl][k8l][col][j] bf16 planes (zero-padded).
__global__ void convert_B(const float* __restrict__ W, unsigned short* __restrict__ out,
                          int K, int NREAL, int KSTEPS, int COLS) {
    const int per = 2 * 4 * COLS * 8;
    long long total = (long long)KSTEPS * per;
    long long i = (long long)blockIdx.x * blockDim.x + threadIdx.x;
    long long stride = (long long)gridDim.x * blockDim.x;
    for (; i < total; i += stride) {
        int s = (int)(i / per);
        int r = (int)(i % per);
        int hl = r / (4 * COLS * 8); r %= 4 * COLS * 8;
        int k8 = r / (COLS * 8);     r %= COLS * 8;
        int col = r >> 3, j = r & 7;
        int k = s * 32 + k8 * 8 + j;
        float v = (k < K && col < NREAL) ? W[(size_t)k * NREAL + col] : 0.f;
        __bf16 hi, lo;
        split_bf16(v, hi, lo);
        out[i] = bf16_bits(hl ? lo : hi);
    }
}

// =================== fp32 tiled GEMM (fallback path only) ===================
__global__ void gemm_tiled(const float* __restrict__ A, const float* __restrict__ B,
                           const float* __restrict__ bias, float* __restrict__ C,
                           int M, int K, int N, int tilesN) {
    const int bx = blockIdx.x % tilesN;
    const int by = blockIdx.x / tilesN;
    const int tid = threadIdx.x;
    const int tx = tid & 15, ty = tid >> 4;
    __shared__ float Asf[64][17];
    __shared__ float Bsf[16][65];
    float acc[4][4] = {};
    const int row0 = by * 64, col0 = bx * 64;
    for (int k0 = 0; k0 < K; k0 += 16) {
        #pragma unroll
        for (int l = 0; l < 4; ++l) {
            int e = tid + l * 256;
            int r = e >> 4, kk = e & 15;
            int gr = row0 + r, gk = k0 + kk;
            Asf[r][kk] = (gr < M && gk < K) ? A[(size_t)gr * K + gk] : 0.f;
        }
        #pragma unroll
        for (int l = 0; l < 4; ++l) {
            int e = tid + l * 256;
            int kk = e >> 6, c = e & 63;
            int gk = k0 + kk, gc = col0 + c;
            Bsf[kk][c] = (gk < K && gc < N) ? B[(size_t)gk * N + gc] : 0.f;
        }
        __syncthreads();
        #pragma unroll
        for (int kk = 0; kk < 16; ++kk) {
            float a[4], b[4];
            #pragma unroll
            for (int i = 0; i < 4; ++i) a[i] = Asf[ty + 16 * i][kk];
            #pragma unroll
            for (int j = 0; j < 4; ++j) b[j] = Bsf[kk][tx + 16 * j];
            #pragma unroll
            for (int i = 0; i < 4; ++i)
                #pragma unroll
                for (int j = 0; j < 4; ++j) acc[i][j] += a[i] * b[j];
        }
        __syncthreads();
    }
    #pragma unroll
    for (int i = 0; i < 4; ++i) {
        int gr = row0 + ty + 16 * i;
        if (gr >= M) continue;
        #pragma unroll
        for (int j = 0; j < 4; ++j) {
            int gc = col0 + tx + 16 * j;
            if (gc >= N) continue;
            float v = acc[i][j];
            if (bias) v += bias[gc];
            C[(size_t)gr * N + gc] = v;
        }
    }
}

// =================== CSR build ===================
__global__ void zero_ints(int* __restrict__ p, int n) {
    int i = blockIdx.x * blockDim.x + threadIdx.x;
    int stride = gridDim.x * blockDim.x;
    for (; i < n; i += stride) p[i] = 0;
}

__global__ void hist_dst(const int* __restrict__ dst, int* __restrict__ counts, int E) {
    int i = blockIdx.x * blockDim.x + threadIdx.x;
    int stride = gridDim.x * blockDim.x;
    for (; i < E; i += stride) atomicAdd(&counts[dst[i]], 1);
}

__global__ void chunk_sums(const int* __restrict__ counts, int* __restrict__ csum, int N) {
    __shared__ int s[256];
    int b = blockIdx.x, t = threadIdx.x;
    int base = b * 2048 + t * 8;
    int loc = 0;
    #pragma unroll
    for (int i = 0; i < 8; ++i) {
        int gi = base + i;
        if (gi < N) loc += counts[gi];
    }
    s[t] = loc;
    __syncthreads();
    for (int off = 128; off > 0; off >>= 1) {
        if (t < off) s[t] += s[t + off];
        __syncthreads();
    }
    if (t == 0) csum[b] = s[0];
}

__global__ void scan_chunks(const int* __restrict__ csum, int* __restrict__ cbase, int NB) {
    if (blockIdx.x == 0 && threadIdx.x == 0) {
        int run = 0;
        for (int b = 0; b < NB; ++b) { cbase[b] = run; run += csum[b]; }
    }
}

__global__ void scan_final(const int* __restrict__ counts, const int* __restrict__ cbase,
                           int* __restrict__ row_start, int* __restrict__ cursor, int N) {
    __shared__ int s[256];
    int b = blockIdx.x, t = threadIdx.x;
    int base = b * 2048 + t * 8;
    int loc = 0;
    #pragma unroll
    for (int i = 0; i < 8; ++i) {
        int gi = base + i;
        if (gi < N) loc += counts[gi];
    }
    s[t] = loc;
    __syncthreads();
    for (int off = 1; off < 256; off <<= 1) {
        int v = (t >= off) ? s[t - off] : 0;
        __syncthreads();
        s[t] += v;
        __syncthreads();
    }
    int run = cbase[b] + s[t] - loc;
    for (int i = 0; i < 8; ++i) {
        int gi = base + i;
        if (gi < N) {
            row_start[gi] = run;
            cursor[gi] = run;
            run += counts[gi];
        }
    }
}

__global__ void scatter_edges(const int* __restrict__ src, const int* __restrict__ dst,
                              const float* __restrict__ w, int* __restrict__ cursor,
                              int2* __restrict__ csr, int E) {
    int i = blockIdx.x * blockDim.x + threadIdx.x;
    int stride = gridDim.x * blockDim.x;
    for (; i < E; i += stride) {
        int d = dst[i];
        int pos = atomicAdd(&cursor[d], 1);
        csr[pos] = make_int2(src[i], __float_as_int(w[i]));
    }
}

// =================== CSR SPMM layer 1 ===================
// nt loads for streaming csr meta, nt store for output: keep h resident in L3.
template <int D, bool RELU>
__global__ __launch_bounds__(256)
void spmm_csr(const float* __restrict__ h, const i32x2* __restrict__ csr,
              const int* __restrict__ row_start, const int* __restrict__ counts,
              const float* __restrict__ bias, float* __restrict__ out, int N) {
    constexpr int VF = D / 4;        // float4 chunks per row
    constexpr int G = 256 / VF;      // rows per block
    const int g = threadIdx.x / VF;
    const int slot = threadIdx.x - g * VF;
    if (g >= G) return;
    const int row = blockIdx.x * G + g;
    if (row >= N) return;

    const int p = row_start[row], len = counts[row];
    f32x4 acc = ((const f32x4*)bias)[slot];

    i32x2 e0 = (i32x2){0, 0}, e1 = e0, e2 = e0, e3 = e0;
    if (len > 0) e0 = __builtin_nontemporal_load(&csr[p]);
    if (len > 1) e1 = __builtin_nontemporal_load(&csr[p + 1]);
    if (len > 2) e2 = __builtin_nontemporal_load(&csr[p + 2]);
    if (len > 3) e3 = __builtin_nontemporal_load(&csr[p + 3]);

    for (int q = 0; q < len; q += 4) {
        const i32x2 c0 = e0, c1 = e1, c2 = e2, c3 = e3;
        const int rem = len - q;
        if (q + 4 < len) e0 = __builtin_nontemporal_load(&csr[p + q + 4]);
        if (q + 5 < len) e1 = __builtin_nontemporal_load(&csr[p + q + 5]);
        if (q + 6 < len) e2 = __builtin_nontemporal_load(&csr[p + q + 6]);
        if (q + 7 < len) e3 = __builtin_nontemporal_load(&csr[p + q + 7]);
        f32x4 h0 = ((const f32x4*)(h + (size_t)c0.x * D))[slot];
        acc += h0 * __int_as_float(c0.y);
        if (rem > 1) {
            f32x4 h1 = ((const f32x4*)(h + (size_t)c1.x * D))[slot];
            acc += h1 * __int_as_float(c1.y);
        }
        if (rem > 2) {
            f32x4 h2 = ((const f32x4*)(h + (size_t)c2.x * D))[slot];
            acc += h2 * __int_as_float(c2.y);
        }
        if (rem > 3) {
            f32x4 h3 = ((const f32x4*)(h + (size_t)c3.x * D))[slot];
            acc += h3 * __int_as_float(c3.y);
        }
    }
    if (RELU) {
        #pragma unroll
        for (int c = 0; c < 4; ++c) acc[c] = acc[c] > 0.f ? acc[c] : 0.f;
    }
    __builtin_nontemporal_store(acc, (f32x4*)(out + (size_t)row * D) + slot);
}

// =================== CSR SPMM layer 2 + fused FC ===================
template <int D, int NCOL>
__global__ __launch_bounds__(256)
void spmm_fc(const float* __restrict__ h, const i32x2* __restrict__ csr,
             const int* __restrict__ row_start, const int* __restrict__ counts,
             const float* __restrict__ bias, const float* __restrict__ Wfc,
             const float* __restrict__ bfc, float* __restrict__ out, int N) {
    constexpr int VF = D / 4;        // 20 lanes per row
    constexpr int G = 256 / VF;      // 12 rows per block
    __shared__ float sh[G][D];
    __shared__ float sW[D * NCOL];
    __shared__ float sb[NCOL];
    for (int i = threadIdx.x; i < D * NCOL; i += 256) sW[i] = Wfc[i];
    if (threadIdx.x < NCOL) sb[threadIdx.x] = bfc[threadIdx.x];

    const int g = threadIdx.x / VF;
    const int slot = threadIdx.x - g * VF;
    const int row = blockIdx.x * G + g;
    const bool active = (g < G) && (row < N);

    if (active) {
        const int p = row_start[row], len = counts[row];
        f32x4 acc = ((const f32x4*)bias)[slot];
        i32x2 e0 = (i32x2){0, 0}, e1 = e0, e2 = e0, e3 = e0;
        if (len > 0) e0 = __builtin_nontemporal_load(&csr[p]);
        if (len > 1) e1 = __builtin_nontemporal_load(&csr[p + 1]);
        if (len > 2) e2 = __builtin_nontemporal_load(&csr[p + 2]);
        if (len > 3) e3 = __builtin_nontemporal_load(&csr[p + 3]);
        for (int q = 0; q < len; q += 4) {
            const i32x2 c0 = e0, c1 = e1, c2 = e2, c3 = e3;
            const int rem = len - q;
            if (q + 4 < len) e0 = __builtin_nontemporal_load(&csr[p + q + 4]);
            if (q + 5 < len) e1 = __builtin_nontemporal_load(&csr[p + q + 5]);
            if (q + 6 < len) e2 = __builtin_nontemporal_load(&csr[p + q + 6]);
            if (q + 7 < len) e3 = __builtin_nontemporal_load(&csr[p + q + 7]);
            f32x4 h0 = ((const f32x4*)(h + (size_t)c0.x * D))[slot];
            acc += h0 * __int_as_float(c0.y);
            if (rem > 1) {
                f32x4 h1 = ((const f32x4*)(h + (size_t)c1.x * D))[slot];
                acc += h1 * __int_as_float(c1.y);
            }
            if (rem > 2) {
                f32x4 h2 = ((const f32x4*)(h + (size_t)c2.x * D))[slot];
                acc += h2 * __int_as_float(c2.y);
            }
            if (rem > 3) {
                f32x4 h3 = ((const f32x4*)(h + (size_t)c3.x * D))[slot];
                acc += h3 * __int_as_float(c3.y);
            }
        }
        #pragma unroll
        for (int c = 0; c < 4; ++c) acc[c] = acc[c] > 0.f ? acc[c] : 0.f;
        ((f32x4*)&sh[g][0])[slot] = acc;
    }
    __syncthreads();

    const int idx = threadIdx.x;
    if (idx < G * NCOL) {
        const int gr = idx / NCOL, c = idx - gr * NCOL;
        const int orow = blockIdx.x * G + gr;
        if (orow < N) {
            float s = sb[c];
            #pragma unroll 8
            for (int j = 0; j < D; ++j) s += sh[gr][j] * sW[j * NCOL + c];
            out[(size_t)orow * NCOL + c] = s;
        }
    }
}

// =================== fallback SPMM (atomic) ===================
__global__ void init_bias_kernel(float* __restrict__ agg, const float* __restrict__ bias,
                                 long long n, int D) {
    long long i = (long long)blockIdx.x * blockDim.x + threadIdx.x;
    long long stride = (long long)gridDim.x * blockDim.x;
    for (; i < n; i += stride) agg[i] = bias[(int)(i % D)];
}

template <int D>
__global__ void spmm_edges(const float* __restrict__ h, const int* __restrict__ src,
                           const int* __restrict__ dst, const float* __restrict__ w,
                           float* __restrict__ agg, int E) {
    int e = blockIdx.x * 4 + (threadIdx.x >> 6);
    int lane = threadIdx.x & 63;
    if (e >= E) return;
    int s = src[e], d = dst[e];
    float wt = w[e];
    const float* hs = h + (size_t)s * D;
    float* ad = agg + (size_t)d * D;
    for (int j = lane; j < D; j += 64) atomicAdd(&ad[j], wt * hs[j]);
}

__global__ void relu_kernel(float* __restrict__ x, long long n) {
    long long i = (long long)blockIdx.x * blockDim.x + threadIdx.x;
    long long stride = (long long)gridDim.x * blockDim.x;
    for (; i < n; i += stride) {
        float v = x[i];
        x[i] = v > 0.f ? v : 0.f;
    }
}

extern "C" void kernel_launch(void* const* d_in, const int* in_sizes, int n_in,
                              void* d_out, int out_size, void* d_ws, size_t ws_size,
                              hipStream_t stream) {
    const float* x        = (const float*)d_in[0];
    const int*   edge_src = (const int*)d_in[1];
    const int*   edge_dst = (const int*)d_in[2];
    const float* edge_w   = (const float*)d_in[3];
    const float* W1       = (const float*)d_in[4];
    const float* b1       = (const float*)d_in[5];
    const float* W2       = (const float*)d_in[6];
    const float* b2       = (const float*)d_in[7];
    const float* Wfc      = (const float*)d_in[8];
    const float* bfc      = (const float*)d_in[9];
    float* out = (float*)d_out;

    const int N = in_sizes[0] / F_IN;   // 100000
    const int E = in_sizes[1];          // 3200000
    const int NB = (N + 2047) / 2048;

    // ---- workspace layout ----
    float* h0  = (float*)d_ws;                       // N*H1
    float* agg = h0 + (size_t)N * H1;                // N*H1
    int* counts    = (int*)(agg + (size_t)N * H1);   // N
    int* row_start = counts + N;                     // N
    int* cursor    = row_start + N;                  // N
    int* csum      = cursor + N;                     // NB
    int* cbase     = csum + NB;                      // NB
    size_t csr_off = (size_t)(cbase + NB) - (size_t)d_ws;
    csr_off = (csr_off + 15) & ~(size_t)15;
    int2* csr = (int2*)((char*)d_ws + csr_off);      // E int2
    size_t boff = csr_off + (size_t)E * sizeof(int2);
    boff = (boff + 15) & ~(size_t)15;
    // Bpre sizes (shorts): per-step = 2*4*COLS*8
    const size_t B1n = 45ull * 2 * 4 * 224 * 8;
    const size_t B2n = 7ull * 2 * 4 * 80 * 8;
    unsigned short* B1p = (unsigned short*)((char*)d_ws + boff);
    unsigned short* B2p = B1p + B1n;
    size_t needed = boff + (B1n + B2n) * sizeof(unsigned short);

    float* h1 = agg;
    float* h2 = h0;

    const int MB = (N + 127) / 128;   // 782 (128-row tiles)

    if (ws_size >= needed) {
        // ---- weight pre-convert (hi/lo bf16, per-step staged order) ----
        convert_B<<<(int)((B1n + 255) / 256), 256, 0, stream>>>(W1, B1p, F_IN, H1, 45, 224);
        convert_B<<<(int)((B2n + 255) / 256), 256, 0, stream>>>(W2, B2p, H1, H2, 7, 80);

        // ---- CSR build ----
        zero_ints<<<256, 256, 0, stream>>>(counts, N);
        hist_dst<<<2048, 256, 0, stream>>>(edge_dst, counts, E);
        chunk_sums<<<NB, 256, 0, stream>>>(counts, csum, N);
        scan_chunks<<<1, 64, 0, stream>>>(csum, cbase, NB);
        scan_final<<<NB, 256, 0, stream>>>(counts, cbase, row_start, cursor, N);
        scatter_edges<<<2048, 256, 0, stream>>>(edge_src, edge_dst, edge_w, cursor, csr, E);

        // ---- Layer 1 ----
        gemm_mfma_dbuf<F_IN, 45, 224, 4, 2, 2, 7, false><<<MB, 512, 0, stream>>>(x, B1p, nullptr, h0, N, H1);
        {
            constexpr int G1 = 256 / (H1 / 4);   // 5 rows/block
            spmm_csr<H1, true><<<(N + G1 - 1) / G1, 256, 0, stream>>>(h0, (const i32x2*)csr, row_start, counts, b1, h1, N);
        }

        // ---- Layer 2 ----
        gemm_mfma_dbuf<H1, 7, 80, 8, 1, 1, 5, false><<<MB, 512, 0, stream>>>(h1, B2p, nullptr, h2, N, H2);

        // ---- Layer-2 SPMM + fused FC ----
        {
            constexpr int G2 = 256 / (H2 / 4);   // 12 rows/block
            spmm_fc<H2, NC><<<(N + G2 - 1) / G2, 256, 0, stream>>>(h2, (const i32x2*)csr, row_start, counts, b2, Wfc, bfc, out, N);
        }
    } else {
        // ---- fallback: fp32 everything, atomic SPMM ----
        const int tilesM = (N + 63) / 64;
        gemm_tiled<<<tilesM * 4, 256, 0, stream>>>(x, W1, nullptr, h0, N, F_IN, H1, 4);
        init_bias_kernel<<<2048, 256, 0, stream>>>(agg, b1, (long long)N * H1, H1);
        spmm_edges<H1><<<(E + 3) / 4, 256, 0, stream>>>(h0, edge_src, edge_dst, edge_w, agg, E);
        relu_kernel<<<2048, 256, 0, stream>>>(agg, (long long)N * H1);
        gemm_tiled<<<tilesM * 2, 256, 0, stream>>>(h1, W2, nullptr, h2, N, H1, H2, 2);
        init_bias_kernel<<<2048, 256, 0, stream>>>(agg, b2, (long long)N * H2, H2);
        spmm_edges<H2><<<(E + 3) / 4, 256, 0, stream>>>(h2, edge_src, edge_dst, edge_w, agg, E);
        relu_kernel<<<2048, 256, 0, stream>>>(agg, (long long)N * H2);
        gemm_tiled<<<tilesM, 256, 0, stream>>>(agg, Wfc, bfc, out, N, H2, NC, 1);
    }
}

// Round 10
// 1223.189 us; speedup vs baseline: 1.0928x; 1.0928x over previous
//
#include <hip/hip_runtime.h>

#define F_IN 1433
#define H1 200
#define H2 80
#define NC 7

typedef __bf16 bf16x8 __attribute__((ext_vector_type(8)));
typedef float f32x4 __attribute__((ext_vector_type(4)));

__device__ __forceinline__ unsigned short bf16_bits(__bf16 h) {
    union { __bf16 h; unsigned short u; } c; c.h = h; return c.u;
}
__device__ __forceinline__ void split_bf16(float a, __bf16& hi, __bf16& lo) {
    hi = (__bf16)a;
    lo = (__bf16)(a - (float)hi);
}

struct AF { float v[8]; };

__device__ __forceinline__ void glds16(const void* g, void* l) {
    __builtin_amdgcn_global_load_lds(
        (const __attribute__((address_space(1))) unsigned int*)g,
        (__attribute__((address_space(3))) unsigned int*)l, 16, 0, 0);
}

// =================== split-bf16 MFMA GEMM (round-7 exact: single-buffer, 512 thr) ===================
// C[M][NREAL] = A[M][K] @ B[K][NREAL]. Bpre layout (shorts), per k-step s:
//   Bpre[s][hl][k8l][col][j]  (PER_STEP = 2*4*COLS*8 shorts, zero-padded)
// Block: 512 thr = 8 waves as WR x WC grid over a 128 x COLS tile.
// A: per-lane direct global loads (row l&15, k-slice (l>>4)*8), 1-step register prefetch.
// B: cooperative glds16 into single-buffer LDS, 2 barriers per step (m97 pattern).
template <int K, int KSTEPS, int COLS, int WR, int WC, int MT, int NT, bool BIAS>
__global__ __launch_bounds__(512, 4)
void gemm_mfma_bstage(const float* __restrict__ A, const unsigned short* __restrict__ Bpre,
                      const float* __restrict__ bias, float* __restrict__ C,
                      int M, int NREAL) {
    static_assert(WR * WC == 8, "8 waves");
    static_assert(WR * MT * 16 == 128, "rows");
    static_assert(WC * NT * 16 == COLS, "cols");
    constexpr int THREADS = 512;
    constexpr int PER_STEP = 2 * 4 * COLS * 8;   // shorts per k-step
    constexpr int CH = COLS * 8;                 // 16B chunks per k-step
    constexpr bool PART = (KSTEPS * 32 > K);

    __shared__ alignas(16) unsigned short Bs[PER_STEP];

    const int tid = threadIdx.x;
    const int wave = tid >> 6, lane = tid & 63;
    const int l15 = lane & 15, l4 = lane >> 4;
    const int wr = wave / WC, wc = wave % WC;
    const int row0 = blockIdx.x * 128 + wr * (MT * 16);
    const int colbase = wc * (NT * 16);

    f32x4 acc[MT][NT];
    #pragma unroll
    for (int m = 0; m < MT; ++m)
        #pragma unroll
        for (int n = 0; n < NT; ++n) acc[m][n] = (f32x4){0.f, 0.f, 0.f, 0.f};

    const float* arow[MT];
    #pragma unroll
    for (int m = 0; m < MT; ++m) {
        int r = row0 + m * 16 + l15;
        if (r >= M) r = M - 1;            // clamp; OOB rows masked at store
        arow[m] = A + (size_t)r * K;
    }

    auto loadA = [&](int s, AF* dst) {
        const int kb = s * 32 + l4 * 8;
        #pragma unroll
        for (int m = 0; m < MT; ++m) {
            const float* ap = arow[m] + kb;
            if (PART && s == KSTEPS - 1) {
                #pragma unroll
                for (int j = 0; j < 8; ++j) dst[m].v[j] = (kb + j < K) ? ap[j] : 0.f;
            } else {
                #pragma unroll
                for (int j = 0; j < 8; ++j) dst[m].v[j] = ap[j];
            }
        }
    };

    auto stageB = [&](int s) {
        const unsigned short* src = Bpre + (size_t)s * PER_STEP;
        #pragma unroll 4
        for (int c = tid; c < CH; c += THREADS)
            glds16(src + (size_t)c * 8, &Bs[c * 8]);
    };

    AF aCur[MT], aNxt[MT];
    loadA(0, aCur);
    stageB(0);

    for (int s = 0; s < KSTEPS; ++s) {
        __syncthreads();                         // B(s) visible in LDS
        bf16x8 aHi[MT], aLo[MT];
        #pragma unroll
        for (int m = 0; m < MT; ++m)
            #pragma unroll
            for (int j = 0; j < 8; ++j) {
                __bf16 hi, lo;
                split_bf16(aCur[m].v[j], hi, lo);
                aHi[m][j] = hi;
                aLo[m][j] = lo;
            }
        if (s + 1 < KSTEPS) loadA(s + 1, aNxt);  // A prefetch hides under MFMAs

        #pragma unroll
        for (int n = 0; n < NT; ++n) {
            const int colb = colbase + n * 16 + l15;
            bf16x8 bHi = *(const bf16x8*)&Bs[((0 + l4) * COLS + colb) * 8];
            bf16x8 bLo = *(const bf16x8*)&Bs[((4 + l4) * COLS + colb) * 8];
            #pragma unroll
            for (int m = 0; m < MT; ++m) {
                acc[m][n] = __builtin_amdgcn_mfma_f32_16x16x32_bf16(aHi[m], bHi, acc[m][n], 0, 0, 0);
                acc[m][n] = __builtin_amdgcn_mfma_f32_16x16x32_bf16(aLo[m], bHi, acc[m][n], 0, 0, 0);
                acc[m][n] = __builtin_amdgcn_mfma_f32_16x16x32_bf16(aHi[m], bLo, acc[m][n], 0, 0, 0);
            }
        }
        __syncthreads();                         // all waves done reading Bs
        if (s + 1 < KSTEPS) stageB(s + 1);
        #pragma unroll
        for (int m = 0; m < MT; ++m) aCur[m] = aNxt[m];
    }

    // epilogue: C/D layout col=lane&15, row=(lane>>4)*4+reg
    #pragma unroll
    for (int m = 0; m < MT; ++m) {
        const int rbase = row0 + m * 16 + l4 * 4;
        #pragma unroll
        for (int n = 0; n < NT; ++n) {
            int col = colbase + n * 16 + l15;
            if (col >= NREAL) continue;
            float bv = BIAS ? bias[col] : 0.f;
            #pragma unroll
            for (int r = 0; r < 4; ++r) {
                int gr = rbase + r;
                if (gr < M) C[(size_t)gr * NREAL + col] = acc[m][n][r] + bv;
            }
        }
    }
}

// Convert W[K][NREAL] fp32 -> Bpre[s][hl][k8l][col][j] bf16 planes (zero-padded).
__global__ void convert_B(const float* __restrict__ W, unsigned short* __restrict__ out,
                          int K, int NREAL, int KSTEPS, int COLS) {
    const int per = 2 * 4 * COLS * 8;
    long long total = (long long)KSTEPS * per;
    long long i = (long long)blockIdx.x * blockDim.x + threadIdx.x;
    long long stride = (long long)gridDim.x * blockDim.x;
    for (; i < total; i += stride) {
        int s = (int)(i / per);
        int r = (int)(i % per);
        int hl = r / (4 * COLS * 8); r %= 4 * COLS * 8;
        int k8 = r / (COLS * 8);     r %= COLS * 8;
        int col = r >> 3, j = r & 7;
        int k = s * 32 + k8 * 8 + j;
        float v = (k < K && col < NREAL) ? W[(size_t)k * NREAL + col] : 0.f;
        __bf16 hi, lo;
        split_bf16(v, hi, lo);
        out[i] = bf16_bits(hl ? lo : hi);
    }
}

// =================== fp32 tiled GEMM (fallback path only) ===================
__global__ void gemm_tiled(const float* __restrict__ A, const float* __restrict__ B,
                           const float* __restrict__ bias, float* __restrict__ C,
                           int M, int K, int N, int tilesN) {
    const int bx = blockIdx.x % tilesN;
    const int by = blockIdx.x / tilesN;
    const int tid = threadIdx.x;
    const int tx = tid & 15, ty = tid >> 4;
    __shared__ float Asf[64][17];
    __shared__ float Bsf[16][65];
    float acc[4][4] = {};
    const int row0 = by * 64, col0 = bx * 64;
    for (int k0 = 0; k0 < K; k0 += 16) {
        #pragma unroll
        for (int l = 0; l < 4; ++l) {
            int e = tid + l * 256;
            int r = e >> 4, kk = e & 15;
            int gr = row0 + r, gk = k0 + kk;
            Asf[r][kk] = (gr < M && gk < K) ? A[(size_t)gr * K + gk] : 0.f;
        }
        #pragma unroll
        for (int l = 0; l < 4; ++l) {
            int e = tid + l * 256;
            int kk = e >> 6, c = e & 63;
            int gk = k0 + kk, gc = col0 + c;
            Bsf[kk][c] = (gk < K && gc < N) ? B[(size_t)gk * N + gc] : 0.f;
        }
        __syncthreads();
        #pragma unroll
        for (int kk = 0; kk < 16; ++kk) {
            float a[4], b[4];
            #pragma unroll
            for (int i = 0; i < 4; ++i) a[i] = Asf[ty + 16 * i][kk];
            #pragma unroll
            for (int j = 0; j < 4; ++j) b[j] = Bsf[kk][tx + 16 * j];
            #pragma unroll
            for (int i = 0; i < 4; ++i)
                #pragma unroll
                for (int j = 0; j < 4; ++j) acc[i][j] += a[i] * b[j];
        }
        __syncthreads();
    }
    #pragma unroll
    for (int i = 0; i < 4; ++i) {
        int gr = row0 + ty + 16 * i;
        if (gr >= M) continue;
        #pragma unroll
        for (int j = 0; j < 4; ++j) {
            int gc = col0 + tx + 16 * j;
            if (gc >= N) continue;
            float v = acc[i][j];
            if (bias) v += bias[gc];
            C[(size_t)gr * N + gc] = v;
        }
    }
}

// =================== CSR build ===================
__global__ void zero_ints(int* __restrict__ p, int n) {
    int i = blockIdx.x * blockDim.x + threadIdx.x;
    int stride = gridDim.x * blockDim.x;
    for (; i < n; i += stride) p[i] = 0;
}

__global__ void hist_dst(const int* __restrict__ dst, int* __restrict__ counts, int E) {
    int i = blockIdx.x * blockDim.x + threadIdx.x;
    int stride = gridDim.x * blockDim.x;
    for (; i < E; i += stride) atomicAdd(&counts[dst[i]], 1);
}

__global__ void chunk_sums(const int* __restrict__ counts, int* __restrict__ csum, int N) {
    __shared__ int s[256];
    int b = blockIdx.x, t = threadIdx.x;
    int base = b * 2048 + t * 8;
    int loc = 0;
    #pragma unroll
    for (int i = 0; i < 8; ++i) {
        int gi = base + i;
        if (gi < N) loc += counts[gi];
    }
    s[t] = loc;
    __syncthreads();
    for (int off = 128; off > 0; off >>= 1) {
        if (t < off) s[t] += s[t + off];
        __syncthreads();
    }
    if (t == 0) csum[b] = s[0];
}

__global__ void scan_chunks(const int* __restrict__ csum, int* __restrict__ cbase, int NB) {
    if (blockIdx.x == 0 && threadIdx.x == 0) {
        int run = 0;
        for (int b = 0; b < NB; ++b) { cbase[b] = run; run += csum[b]; }
    }
}

__global__ void scan_final(const int* __restrict__ counts, const int* __restrict__ cbase,
                           int* __restrict__ row_start, int* __restrict__ cursor, int N) {
    __shared__ int s[256];
    int b = blockIdx.x, t = threadIdx.x;
    int base = b * 2048 + t * 8;
    int loc = 0;
    #pragma unroll
    for (int i = 0; i < 8; ++i) {
        int gi = base + i;
        if (gi < N) loc += counts[gi];
    }
    s[t] = loc;
    __syncthreads();
    for (int off = 1; off < 256; off <<= 1) {
        int v = (t >= off) ? s[t - off] : 0;
        __syncthreads();
        s[t] += v;
        __syncthreads();
    }
    int run = cbase[b] + s[t] - loc;
    for (int i = 0; i < 8; ++i) {
        int gi = base + i;
        if (gi < N) {
            row_start[gi] = run;
            cursor[gi] = run;
            run += counts[gi];
        }
    }
}

__global__ void scatter_edges(const int* __restrict__ src, const int* __restrict__ dst,
                              const float* __restrict__ w, int* __restrict__ cursor,
                              int2* __restrict__ csr, int E) {
    int i = blockIdx.x * blockDim.x + threadIdx.x;
    int stride = gridDim.x * blockDim.x;
    for (; i < E; i += stride) {
        int d = dst[i];
        int pos = atomicAdd(&cursor[d], 1);
        csr[pos] = make_int2(src[i], __float_as_int(w[i]));
    }
}

// =================== CSR SPMM layer 1: G rows/block, D/4 lanes per row ===================
template <int D, bool RELU>
__global__ __launch_bounds__(256)
void spmm_csr(const float* __restrict__ h, const int2* __restrict__ csr,
              const int* __restrict__ row_start, const int* __restrict__ counts,
              const float* __restrict__ bias, float* __restrict__ out, int N) {
    constexpr int VF = D / 4;        // float4 chunks per row
    constexpr int G = 256 / VF;      // rows per block
    const int g = threadIdx.x / VF;
    const int slot = threadIdx.x - g * VF;
    if (g >= G) return;
    const int row = blockIdx.x * G + g;
    if (row >= N) return;

    const int p = row_start[row], len = counts[row];
    f32x4 acc = ((const f32x4*)bias)[slot];

    int2 e0 = make_int2(0, 0), e1 = e0, e2 = e0, e3 = e0;
    if (len > 0) e0 = csr[p];
    if (len > 1) e1 = csr[p + 1];
    if (len > 2) e2 = csr[p + 2];
    if (len > 3) e3 = csr[p + 3];

    for (int q = 0; q < len; q += 4) {
        const int2 c0 = e0, c1 = e1, c2 = e2, c3 = e3;
        const int rem = len - q;
        if (q + 4 < len) e0 = csr[p + q + 4];
        if (q + 5 < len) e1 = csr[p + q + 5];
        if (q + 6 < len) e2 = csr[p + q + 6];
        if (q + 7 < len) e3 = csr[p + q + 7];
        f32x4 h0 = ((const f32x4*)(h + (size_t)c0.x * D))[slot];
        acc += h0 * __int_as_float(c0.y);
        if (rem > 1) {
            f32x4 h1 = ((const f32x4*)(h + (size_t)c1.x * D))[slot];
            acc += h1 * __int_as_float(c1.y);
        }
        if (rem > 2) {
            f32x4 h2 = ((const f32x4*)(h + (size_t)c2.x * D))[slot];
            acc += h2 * __int_as_float(c2.y);
        }
        if (rem > 3) {
            f32x4 h3 = ((const f32x4*)(h + (size_t)c3.x * D))[slot];
            acc += h3 * __int_as_float(c3.y);
        }
    }
    if (RELU) {
        #pragma unroll
        for (int c = 0; c < 4; ++c) acc[c] = acc[c] > 0.f ? acc[c] : 0.f;
    }
    ((f32x4*)(out + (size_t)row * D))[slot] = acc;
}

// =================== CSR SPMM layer 2 + fused FC ===================
// Aggregated+relu'd 80-dim rows staged to LDS; 84 threads compute the 12x7 logits.
template <int D, int NCOL>
__global__ __launch_bounds__(256)
void spmm_fc(const float* __restrict__ h, const int2* __restrict__ csr,
             const int* __restrict__ row_start, const int* __restrict__ counts,
             const float* __restrict__ bias, const float* __restrict__ Wfc,
             const float* __restrict__ bfc, float* __restrict__ out, int N) {
    constexpr int VF = D / 4;        // 20 lanes per row
    constexpr int G = 256 / VF;      // 12 rows per block
    __shared__ float sh[G][D];
    __shared__ float sW[D * NCOL];
    __shared__ float sb[NCOL];
    for (int i = threadIdx.x; i < D * NCOL; i += 256) sW[i] = Wfc[i];
    if (threadIdx.x < NCOL) sb[threadIdx.x] = bfc[threadIdx.x];

    const int g = threadIdx.x / VF;
    const int slot = threadIdx.x - g * VF;
    const int row = blockIdx.x * G + g;
    const bool active = (g < G) && (row < N);

    if (active) {
        const int p = row_start[row], len = counts[row];
        f32x4 acc = ((const f32x4*)bias)[slot];
        int2 e0 = make_int2(0, 0), e1 = e0, e2 = e0, e3 = e0;
        if (len > 0) e0 = csr[p];
        if (len > 1) e1 = csr[p + 1];
        if (len > 2) e2 = csr[p + 2];
        if (len > 3) e3 = csr[p + 3];
        for (int q = 0; q < len; q += 4) {
            const int2 c0 = e0, c1 = e1, c2 = e2, c3 = e3;
            const int rem = len - q;
            if (q + 4 < len) e0 = csr[p + q + 4];
            if (q + 5 < len) e1 = csr[p + q + 5];
            if (q + 6 < len) e2 = csr[p + q + 6];
            if (q + 7 < len) e3 = csr[p + q + 7];
            f32x4 h0 = ((const f32x4*)(h + (size_t)c0.x * D))[slot];
            acc += h0 * __int_as_float(c0.y);
            if (rem > 1) {
                f32x4 h1 = ((const f32x4*)(h + (size_t)c1.x * D))[slot];
                acc += h1 * __int_as_float(c1.y);
            }
            if (rem > 2) {
                f32x4 h2 = ((const f32x4*)(h + (size_t)c2.x * D))[slot];
                acc += h2 * __int_as_float(c2.y);
            }
            if (rem > 3) {
                f32x4 h3 = ((const f32x4*)(h + (size_t)c3.x * D))[slot];
                acc += h3 * __int_as_float(c3.y);
            }
        }
        #pragma unroll
        for (int c = 0; c < 4; ++c) acc[c] = acc[c] > 0.f ? acc[c] : 0.f;
        ((f32x4*)&sh[g][0])[slot] = acc;
    }
    __syncthreads();

    const int idx = threadIdx.x;
    if (idx < G * NCOL) {
        const int gr = idx / NCOL, c = idx - gr * NCOL;
        const int orow = blockIdx.x * G + gr;
        if (orow < N) {
            float s = sb[c];
            #pragma unroll 8
            for (int j = 0; j < D; ++j) s += sh[gr][j] * sW[j * NCOL + c];
            out[(size_t)orow * NCOL + c] = s;
        }
    }
}

// =================== fallback SPMM (atomic) ===================
__global__ void init_bias_kernel(float* __restrict__ agg, const float* __restrict__ bias,
                                 long long n, int D) {
    long long i = (long long)blockIdx.x * blockDim.x + threadIdx.x;
    long long stride = (long long)gridDim.x * blockDim.x;
    for (; i < n; i += stride) agg[i] = bias[(int)(i % D)];
}

template <int D>
__global__ void spmm_edges(const float* __restrict__ h, const int* __restrict__ src,
                           const int* __restrict__ dst, const float* __restrict__ w,
                           float* __restrict__ agg, int E) {
    int e = blockIdx.x * 4 + (threadIdx.x >> 6);
    int lane = threadIdx.x & 63;
    if (e >= E) return;
    int s = src[e], d = dst[e];
    float wt = w[e];
    const float* hs = h + (size_t)s * D;
    float* ad = agg + (size_t)d * D;
    for (int j = lane; j < D; j += 64) atomicAdd(&ad[j], wt * hs[j]);
}

__global__ void relu_kernel(float* __restrict__ x, long long n) {
    long long i = (long long)blockIdx.x * blockDim.x + threadIdx.x;
    long long stride = (long long)gridDim.x * blockDim.x;
    for (; i < n; i += stride) {
        float v = x[i];
        x[i] = v > 0.f ? v : 0.f;
    }
}

extern "C" void kernel_launch(void* const* d_in, const int* in_sizes, int n_in,
                              void* d_out, int out_size, void* d_ws, size_t ws_size,
                              hipStream_t stream) {
    const float* x        = (const float*)d_in[0];
    const int*   edge_src = (const int*)d_in[1];
    const int*   edge_dst = (const int*)d_in[2];
    const float* edge_w   = (const float*)d_in[3];
    const float* W1       = (const float*)d_in[4];
    const float* b1       = (const float*)d_in[5];
    const float* W2       = (const float*)d_in[6];
    const float* b2       = (const float*)d_in[7];
    const float* Wfc      = (const float*)d_in[8];
    const float* bfc      = (const float*)d_in[9];
    float* out = (float*)d_out;

    const int N = in_sizes[0] / F_IN;   // 100000
    const int E = in_sizes[1];          // 3200000
    const int NB = (N + 2047) / 2048;

    // ---- workspace layout ----
    float* h0  = (float*)d_ws;                       // N*H1
    float* agg = h0 + (size_t)N * H1;                // N*H1
    int* counts    = (int*)(agg + (size_t)N * H1);   // N
    int* row_start = counts + N;                     // N
    int* cursor    = row_start + N;                  // N
    int* csum      = cursor + N;                     // NB
    int* cbase     = csum + NB;                      // NB
    size_t csr_off = (size_t)(cbase + NB) - (size_t)d_ws;
    csr_off = (csr_off + 15) & ~(size_t)15;
    int2* csr = (int2*)((char*)d_ws + csr_off);      // E int2
    size_t boff = csr_off + (size_t)E * sizeof(int2);
    boff = (boff + 15) & ~(size_t)15;
    // Bpre sizes (shorts): per-step = 2*4*COLS*8
    const size_t B1n = 45ull * 2 * 4 * 224 * 8;
    const size_t B2n = 7ull * 2 * 4 * 80 * 8;
    unsigned short* B1p = (unsigned short*)((char*)d_ws + boff);
    unsigned short* B2p = B1p + B1n;
    size_t needed = boff + (B1n + B2n) * sizeof(unsigned short);

    float* h1 = agg;
    float* h2 = h0;

    const int MB = (N + 127) / 128;   // 782 (128-row tiles)

    if (ws_size >= needed) {
        // ---- weight pre-convert (hi/lo bf16, per-step staged order) ----
        convert_B<<<(int)((B1n + 255) / 256), 256, 0, stream>>>(W1, B1p, F_IN, H1, 45, 224);
        convert_B<<<(int)((B2n + 255) / 256), 256, 0, stream>>>(W2, B2p, H1, H2, 7, 80);

        // ---- CSR build ----
        zero_ints<<<256, 256, 0, stream>>>(counts, N);
        hist_dst<<<2048, 256, 0, stream>>>(edge_dst, counts, E);
        chunk_sums<<<NB, 256, 0, stream>>>(counts, csum, N);
        scan_chunks<<<1, 64, 0, stream>>>(csum, cbase, NB);
        scan_final<<<NB, 256, 0, stream>>>(counts, cbase, row_start, cursor, N);
        scatter_edges<<<2048, 256, 0, stream>>>(edge_src, edge_dst, edge_w, cursor, csr, E);

        // ---- Layer 1 ----
        gemm_mfma_bstage<F_IN, 45, 224, 4, 2, 2, 7, false><<<MB, 512, 0, stream>>>(x, B1p, nullptr, h0, N, H1);
        {
            constexpr int G1 = 256 / (H1 / 4);   // 5 rows/block
            spmm_csr<H1, true><<<(N + G1 - 1) / G1, 256, 0, stream>>>(h0, csr, row_start, counts, b1, h1, N);
        }

        // ---- Layer 2 ----
        gemm_mfma_bstage<H1, 7, 80, 8, 1, 1, 5, false><<<MB, 512, 0, stream>>>(h1, B2p, nullptr, h2, N, H2);

        // ---- Layer-2 SPMM + fused FC ----
        {
            constexpr int G2 = 256 / (H2 / 4);   // 12 rows/block
            spmm_fc<H2, NC><<<(N + G2 - 1) / G2, 256, 0, stream>>>(h2, csr, row_start, counts, b2, Wfc, bfc, out, N);
        }
    } else {
        // ---- fallback: fp32 everything, atomic SPMM ----
        const int tilesM = (N + 63) / 64;
        gemm_tiled<<<tilesM * 4, 256, 0, stream>>>(x, W1, nullptr, h0, N, F_IN, H1, 4);
        init_bias_kernel<<<2048, 256, 0, stream>>>(agg, b1, (long long)N * H1, H1);
        spmm_edges<H1><<<(E + 3) / 4, 256, 0, stream>>>(h0, edge_src, edge_dst, edge_w, agg, E);
        relu_kernel<<<2048, 256, 0, stream>>>(agg, (long long)N * H1);
        gemm_tiled<<<tilesM * 2, 256, 0, stream>>>(h1, W2, nullptr, h2, N, H1, H2, 2);
        init_bias_kernel<<<2048, 256, 0, stream>>>(agg, b2, (long long)N * H2, H2);
        spmm_edges<H2><<<(E + 3) / 4, 256, 0, stream>>>(h2, edge_src, edge_dst, edge_w, agg, E);
        relu_kernel<<<2048, 256, 0, stream>>>(agg, (long long)N * H2);
        gemm_tiled<<<tilesM, 256, 0, stream>>>(agg, Wfc, bfc, out, N, H2, NC, 1);
    }
}

// Round 11
// 1205.740 us; speedup vs baseline: 1.1086x; 1.0145x over previous
//
#include <hip/hip_runtime.h>

#define F_IN 1433
#define H1 200
#define H2 80
#define NC 7

typedef __bf16 bf16x8 __attribute__((ext_vector_type(8)));
typedef float f32x4 __attribute__((ext_vector_type(4)));

__device__ __forceinline__ unsigned short bf16_bits(__bf16 h) {
    union { __bf16 h; unsigned short u; } c; c.h = h; return c.u;
}
__device__ __forceinline__ void split_bf16(float a, __bf16& hi, __bf16& lo) {
    hi = (__bf16)a;
    lo = (__bf16)(a - (float)hi);
}

struct AF { float v[8]; };

__device__ __forceinline__ void glds16(const void* g, void* l) {
    __builtin_amdgcn_global_load_lds(
        (const __attribute__((address_space(1))) unsigned int*)g,
        (__attribute__((address_space(3))) unsigned int*)l, 16, 0, 0);
}

// =================== split-bf16 MFMA GEMM (single-buffer, 512 thr, m97 pattern) ===================
// C[M][NREAL] = A[M][K] @ B[K][NREAL]. Bpre layout (shorts), per k-step s:
//   Bpre[s][hl][k8l][col][j]  (PER_STEP = 2*4*COLS*8 shorts, zero-padded)
// Block: 512 thr = 8 waves as WR x WC grid over a 128 x COLS tile.
// A: per-lane direct global loads (row l&15, k-slice (l>>4)*8), 1-step register prefetch.
// B: cooperative glds16 into single-buffer LDS, 2 barriers per step.
template <int K, int KSTEPS, int COLS, int WR, int WC, int MT, int NT, bool BIAS>
__global__ __launch_bounds__(512, 4)
void gemm_mfma_bstage(const float* __restrict__ A, const unsigned short* __restrict__ Bpre,
                      const float* __restrict__ bias, float* __restrict__ C,
                      int M, int NREAL) {
    static_assert(WR * WC == 8, "8 waves");
    static_assert(WR * MT * 16 == 128, "rows");
    static_assert(WC * NT * 16 == COLS, "cols");
    constexpr int THREADS = 512;
    constexpr int PER_STEP = 2 * 4 * COLS * 8;   // shorts per k-step
    constexpr int CH = COLS * 8;                 // 16B chunks per k-step
    constexpr bool PART = (KSTEPS * 32 > K);

    __shared__ alignas(16) unsigned short Bs[PER_STEP];

    const int tid = threadIdx.x;
    const int wave = tid >> 6, lane = tid & 63;
    const int l15 = lane & 15, l4 = lane >> 4;
    const int wr = wave / WC, wc = wave % WC;
    const int row0 = blockIdx.x * 128 + wr * (MT * 16);
    const int colbase = wc * (NT * 16);

    f32x4 acc[MT][NT];
    #pragma unroll
    for (int m = 0; m < MT; ++m)
        #pragma unroll
        for (int n = 0; n < NT; ++n) acc[m][n] = (f32x4){0.f, 0.f, 0.f, 0.f};

    const float* arow[MT];
    #pragma unroll
    for (int m = 0; m < MT; ++m) {
        int r = row0 + m * 16 + l15;
        if (r >= M) r = M - 1;            // clamp; OOB rows masked at store
        arow[m] = A + (size_t)r * K;
    }

    auto loadA = [&](int s, AF* dst) {
        const int kb = s * 32 + l4 * 8;
        #pragma unroll
        for (int m = 0; m < MT; ++m) {
            const float* ap = arow[m] + kb;
            if (PART && s == KSTEPS - 1) {
                #pragma unroll
                for (int j = 0; j < 8; ++j) dst[m].v[j] = (kb + j < K) ? ap[j] : 0.f;
            } else {
                #pragma unroll
                for (int j = 0; j < 8; ++j) dst[m].v[j] = ap[j];
            }
        }
    };

    auto stageB = [&](int s) {
        const unsigned short* src = Bpre + (size_t)s * PER_STEP;
        #pragma unroll 4
        for (int c = tid; c < CH; c += THREADS)
            glds16(src + (size_t)c * 8, &Bs[c * 8]);
    };

    AF aCur[MT], aNxt[MT];
    loadA(0, aCur);
    stageB(0);

    for (int s = 0; s < KSTEPS; ++s) {
        __syncthreads();                         // B(s) visible in LDS
        bf16x8 aHi[MT], aLo[MT];
        #pragma unroll
        for (int m = 0; m < MT; ++m)
            #pragma unroll
            for (int j = 0; j < 8; ++j) {
                __bf16 hi, lo;
                split_bf16(aCur[m].v[j], hi, lo);
                aHi[m][j] = hi;
                aLo[m][j] = lo;
            }
        if (s + 1 < KSTEPS) loadA(s + 1, aNxt);  // A prefetch hides under MFMAs

        #pragma unroll
        for (int n = 0; n < NT; ++n) {
            const int colb = colbase + n * 16 + l15;
            bf16x8 bHi = *(const bf16x8*)&Bs[((0 + l4) * COLS + colb) * 8];
            bf16x8 bLo = *(const bf16x8*)&Bs[((4 + l4) * COLS + colb) * 8];
            #pragma unroll
            for (int m = 0; m < MT; ++m) {
                acc[m][n] = __builtin_amdgcn_mfma_f32_16x16x32_bf16(aHi[m], bHi, acc[m][n], 0, 0, 0);
                acc[m][n] = __builtin_amdgcn_mfma_f32_16x16x32_bf16(aLo[m], bHi, acc[m][n], 0, 0, 0);
                acc[m][n] = __builtin_amdgcn_mfma_f32_16x16x32_bf16(aHi[m], bLo, acc[m][n], 0, 0, 0);
            }
        }
        __syncthreads();                         // all waves done reading Bs
        if (s + 1 < KSTEPS) stageB(s + 1);
        #pragma unroll
        for (int m = 0; m < MT; ++m) aCur[m] = aNxt[m];
    }

    // epilogue: C/D layout col=lane&15, row=(lane>>4)*4+reg
    #pragma unroll
    for (int m = 0; m < MT; ++m) {
        const int rbase = row0 + m * 16 + l4 * 4;
        #pragma unroll
        for (int n = 0; n < NT; ++n) {
            int col = colbase + n * 16 + l15;
            if (col >= NREAL) continue;
            float bv = BIAS ? bias[col] : 0.f;
            #pragma unroll
            for (int r = 0; r < 4; ++r) {
                int gr = rbase + r;
                if (gr < M) C[(size_t)gr * NREAL + col] = acc[m][n][r] + bv;
            }
        }
    }
}

// Convert W[K][NREAL] fp32 -> Bpre[s][hl][k8l][col][j] bf16 planes (zero-padded).
__global__ void convert_B(const float* __restrict__ W, unsigned short* __restrict__ out,
                          int K, int NREAL, int KSTEPS, int COLS) {
    const int per = 2 * 4 * COLS * 8;
    long long total = (long long)KSTEPS * per;
    long long i = (long long)blockIdx.x * blockDim.x + threadIdx.x;
    long long stride = (long long)gridDim.x * blockDim.x;
    for (; i < total; i += stride) {
        int s = (int)(i / per);
        int r = (int)(i % per);
        int hl = r / (4 * COLS * 8); r %= 4 * COLS * 8;
        int k8 = r / (COLS * 8);     r %= COLS * 8;
        int col = r >> 3, j = r & 7;
        int k = s * 32 + k8 * 8 + j;
        float v = (k < K && col < NREAL) ? W[(size_t)k * NREAL + col] : 0.f;
        __bf16 hi, lo;
        split_bf16(v, hi, lo);
        out[i] = bf16_bits(hl ? lo : hi);
    }
}

// =================== fp32 tiled GEMM (fallback path only) ===================
__global__ void gemm_tiled(const float* __restrict__ A, const float* __restrict__ B,
                           const float* __restrict__ bias, float* __restrict__ C,
                           int M, int K, int N, int tilesN) {
    const int bx = blockIdx.x % tilesN;
    const int by = blockIdx.x / tilesN;
    const int tid = threadIdx.x;
    const int tx = tid & 15, ty = tid >> 4;
    __shared__ float Asf[64][17];
    __shared__ float Bsf[16][65];
    float acc[4][4] = {};
    const int row0 = by * 64, col0 = bx * 64;
    for (int k0 = 0; k0 < K; k0 += 16) {
        #pragma unroll
        for (int l = 0; l < 4; ++l) {
            int e = tid + l * 256;
            int r = e >> 4, kk = e & 15;
            int gr = row0 + r, gk = k0 + kk;
            Asf[r][kk] = (gr < M && gk < K) ? A[(size_t)gr * K + gk] : 0.f;
        }
        #pragma unroll
        for (int l = 0; l < 4; ++l) {
            int e = tid + l * 256;
            int kk = e >> 6, c = e & 63;
            int gk = k0 + kk, gc = col0 + c;
            Bsf[kk][c] = (gk < K && gc < N) ? B[(size_t)gk * N + gc] : 0.f;
        }
        __syncthreads();
        #pragma unroll
        for (int kk = 0; kk < 16; ++kk) {
            float a[4], b[4];
            #pragma unroll
            for (int i = 0; i < 4; ++i) a[i] = Asf[ty + 16 * i][kk];
            #pragma unroll
            for (int j = 0; j < 4; ++j) b[j] = Bsf[kk][tx + 16 * j];
            #pragma unroll
            for (int i = 0; i < 4; ++i)
                #pragma unroll
                for (int j = 0; j < 4; ++j) acc[i][j] += a[i] * b[j];
        }
        __syncthreads();
    }
    #pragma unroll
    for (int i = 0; i < 4; ++i) {
        int gr = row0 + ty + 16 * i;
        if (gr >= M) continue;
        #pragma unroll
        for (int j = 0; j < 4; ++j) {
            int gc = col0 + tx + 16 * j;
            if (gc >= N) continue;
            float v = acc[i][j];
            if (bias) v += bias[gc];
            C[(size_t)gr * N + gc] = v;
        }
    }
}

// =================== CSR build ===================
__global__ void hist_dst(const int* __restrict__ dst, int* __restrict__ counts, int E) {
    int i = blockIdx.x * blockDim.x + threadIdx.x;
    int stride = gridDim.x * blockDim.x;
    for (; i < E; i += stride) atomicAdd(&counts[dst[i]], 1);
}

__global__ void chunk_sums(const int* __restrict__ counts, int* __restrict__ csum, int N) {
    __shared__ int s[256];
    int b = blockIdx.x, t = threadIdx.x;
    int base = b * 2048 + t * 8;
    int loc = 0;
    #pragma unroll
    for (int i = 0; i < 8; ++i) {
        int gi = base + i;
        if (gi < N) loc += counts[gi];
    }
    s[t] = loc;
    __syncthreads();
    for (int off = 128; off > 0; off >>= 1) {
        if (t < off) s[t] += s[t + off];
        __syncthreads();
    }
    if (t == 0) csum[b] = s[0];
}

// scan_final: block b computes its chunk base by summing csum[0..b) itself (<=49 adds).
__global__ void scan_final(const int* __restrict__ counts, const int* __restrict__ csum,
                           int* __restrict__ row_start, int* __restrict__ cursor, int N) {
    __shared__ int s[256];
    __shared__ int base_s;
    int b = blockIdx.x, t = threadIdx.x;
    if (t == 0) {
        int run = 0;
        for (int i = 0; i < b; ++i) run += csum[i];
        base_s = run;
    }
    int base = b * 2048 + t * 8;
    int loc = 0;
    #pragma unroll
    for (int i = 0; i < 8; ++i) {
        int gi = base + i;
        if (gi < N) loc += counts[gi];
    }
    s[t] = loc;
    __syncthreads();
    for (int off = 1; off < 256; off <<= 1) {
        int v = (t >= off) ? s[t - off] : 0;
        __syncthreads();
        s[t] += v;
        __syncthreads();
    }
    int run = base_s + s[t] - loc;
    for (int i = 0; i < 8; ++i) {
        int gi = base + i;
        if (gi < N) {
            row_start[gi] = run;
            cursor[gi] = run;
            run += counts[gi];
        }
    }
}

__global__ void scatter_edges(const int* __restrict__ src, const int* __restrict__ dst,
                              const float* __restrict__ w, int* __restrict__ cursor,
                              int2* __restrict__ csr, int E) {
    int i = blockIdx.x * blockDim.x + threadIdx.x;
    int stride = gridDim.x * blockDim.x;
    for (; i < E; i += stride) {
        int d = dst[i];
        int pos = atomicAdd(&cursor[d], 1);
        csr[pos] = make_int2(src[i], __float_as_int(w[i]));
    }
}

// =================== CSR SPMM layer 1: G rows/block, D/4 lanes per row, depth-8 prefetch ===================
template <int D, bool RELU>
__global__ __launch_bounds__(256)
void spmm_csr(const float* __restrict__ h, const int2* __restrict__ csr,
              const int* __restrict__ row_start, const int* __restrict__ counts,
              const float* __restrict__ bias, float* __restrict__ out, int N) {
    constexpr int VF = D / 4;        // float4 chunks per row
    constexpr int G = 256 / VF;      // rows per block
    const int g = threadIdx.x / VF;
    const int slot = threadIdx.x - g * VF;
    if (g >= G) return;
    const int row = blockIdx.x * G + g;
    if (row >= N) return;

    const int p = row_start[row], len = counts[row];
    f32x4 acc = ((const f32x4*)bias)[slot];

    int2 e[8];
    #pragma unroll
    for (int i = 0; i < 8; ++i) e[i] = (len > i) ? csr[p + i] : make_int2(0, 0);

    for (int q = 0; q < len; q += 8) {
        int2 c[8];
        #pragma unroll
        for (int i = 0; i < 8; ++i) c[i] = e[i];
        const int rem = len - q;
        #pragma unroll
        for (int i = 0; i < 8; ++i)
            if (q + 8 + i < len) e[i] = csr[p + q + 8 + i];
        #pragma unroll
        for (int i = 0; i < 8; ++i) {
            if (rem > i) {
                f32x4 hv = ((const f32x4*)(h + (size_t)c[i].x * D))[slot];
                acc += hv * __int_as_float(c[i].y);
            }
        }
    }
    if (RELU) {
        #pragma unroll
        for (int c2 = 0; c2 < 4; ++c2) acc[c2] = acc[c2] > 0.f ? acc[c2] : 0.f;
    }
    ((f32x4*)(out + (size_t)row * D))[slot] = acc;
}

// =================== CSR SPMM layer 2 + fused FC (depth-8 prefetch) ===================
template <int D, int NCOL>
__global__ __launch_bounds__(256)
void spmm_fc(const float* __restrict__ h, const int2* __restrict__ csr,
             const int* __restrict__ row_start, const int* __restrict__ counts,
             const float* __restrict__ bias, const float* __restrict__ Wfc,
             const float* __restrict__ bfc, float* __restrict__ out, int N) {
    constexpr int VF = D / 4;        // 20 lanes per row
    constexpr int G = 256 / VF;      // 12 rows per block
    __shared__ float sh[G][D];
    __shared__ float sW[D * NCOL];
    __shared__ float sb[NCOL];
    for (int i = threadIdx.x; i < D * NCOL; i += 256) sW[i] = Wfc[i];
    if (threadIdx.x < NCOL) sb[threadIdx.x] = bfc[threadIdx.x];

    const int g = threadIdx.x / VF;
    const int slot = threadIdx.x - g * VF;
    const int row = blockIdx.x * G + g;
    const bool active = (g < G) && (row < N);

    if (active) {
        const int p = row_start[row], len = counts[row];
        f32x4 acc = ((const f32x4*)bias)[slot];
        int2 e[8];
        #pragma unroll
        for (int i = 0; i < 8; ++i) e[i] = (len > i) ? csr[p + i] : make_int2(0, 0);
        for (int q = 0; q < len; q += 8) {
            int2 c[8];
            #pragma unroll
            for (int i = 0; i < 8; ++i) c[i] = e[i];
            const int rem = len - q;
            #pragma unroll
            for (int i = 0; i < 8; ++i)
                if (q + 8 + i < len) e[i] = csr[p + q + 8 + i];
            #pragma unroll
            for (int i = 0; i < 8; ++i) {
                if (rem > i) {
                    f32x4 hv = ((const f32x4*)(h + (size_t)c[i].x * D))[slot];
                    acc += hv * __int_as_float(c[i].y);
                }
            }
        }
        #pragma unroll
        for (int c2 = 0; c2 < 4; ++c2) acc[c2] = acc[c2] > 0.f ? acc[c2] : 0.f;
        ((f32x4*)&sh[g][0])[slot] = acc;
    }
    __syncthreads();

    const int idx = threadIdx.x;
    if (idx < G * NCOL) {
        const int gr = idx / NCOL, c = idx - gr * NCOL;
        const int orow = blockIdx.x * G + gr;
        if (orow < N) {
            float s = sb[c];
            #pragma unroll 8
            for (int j = 0; j < D; ++j) s += sh[gr][j] * sW[j * NCOL + c];
            out[(size_t)orow * NCOL + c] = s;
        }
    }
}

// =================== fallback SPMM (atomic) ===================
__global__ void init_bias_kernel(float* __restrict__ agg, const float* __restrict__ bias,
                                 long long n, int D) {
    long long i = (long long)blockIdx.x * blockDim.x + threadIdx.x;
    long long stride = (long long)gridDim.x * blockDim.x;
    for (; i < n; i += stride) agg[i] = bias[(int)(i % D)];
}

template <int D>
__global__ void spmm_edges(const float* __restrict__ h, const int* __restrict__ src,
                           const int* __restrict__ dst, const float* __restrict__ w,
                           float* __restrict__ agg, int E) {
    int e = blockIdx.x * 4 + (threadIdx.x >> 6);
    int lane = threadIdx.x & 63;
    if (e >= E) return;
    int s = src[e], d = dst[e];
    float wt = w[e];
    const float* hs = h + (size_t)s * D;
    float* ad = agg + (size_t)d * D;
    for (int j = lane; j < D; j += 64) atomicAdd(&ad[j], wt * hs[j]);
}

__global__ void relu_kernel(float* __restrict__ x, long long n) {
    long long i = (long long)blockIdx.x * blockDim.x + threadIdx.x;
    long long stride = (long long)gridDim.x * blockDim.x;
    for (; i < n; i += stride) {
        float v = x[i];
        x[i] = v > 0.f ? v : 0.f;
    }
}

extern "C" void kernel_launch(void* const* d_in, const int* in_sizes, int n_in,
                              void* d_out, int out_size, void* d_ws, size_t ws_size,
                              hipStream_t stream) {
    const float* x        = (const float*)d_in[0];
    const int*   edge_src = (const int*)d_in[1];
    const int*   edge_dst = (const int*)d_in[2];
    const float* edge_w   = (const float*)d_in[3];
    const float* W1       = (const float*)d_in[4];
    const float* b1       = (const float*)d_in[5];
    const float* W2       = (const float*)d_in[6];
    const float* b2       = (const float*)d_in[7];
    const float* Wfc      = (const float*)d_in[8];
    const float* bfc      = (const float*)d_in[9];
    float* out = (float*)d_out;

    const int N = in_sizes[0] / F_IN;   // 100000
    const int E = in_sizes[1];          // 3200000
    const int NB = (N + 2047) / 2048;

    // ---- workspace layout ----
    float* h0  = (float*)d_ws;                       // N*H1
    float* agg = h0 + (size_t)N * H1;                // N*H1
    int* counts    = (int*)(agg + (size_t)N * H1);   // N
    int* row_start = counts + N;                     // N
    int* cursor    = row_start + N;                  // N
    int* csum      = cursor + N;                     // NB
    size_t csr_off = (size_t)(csum + NB) - (size_t)d_ws;
    csr_off = (csr_off + 15) & ~(size_t)15;
    int2* csr = (int2*)((char*)d_ws + csr_off);      // E int2
    size_t boff = csr_off + (size_t)E * sizeof(int2);
    boff = (boff + 15) & ~(size_t)15;
    // Bpre sizes (shorts): per-step = 2*4*COLS*8
    const size_t B1n = 45ull * 2 * 4 * 224 * 8;
    const size_t B2n = 7ull * 2 * 4 * 80 * 8;
    unsigned short* B1p = (unsigned short*)((char*)d_ws + boff);
    unsigned short* B2p = B1p + B1n;
    size_t needed = boff + (B1n + B2n) * sizeof(unsigned short);

    float* h1 = agg;
    float* h2 = h0;

    const int MB = (N + 127) / 128;   // 782 (128-row tiles)

    if (ws_size >= needed) {
        // ---- weight pre-convert (hi/lo bf16, per-step staged order) ----
        convert_B<<<(int)((B1n + 255) / 256), 256, 0, stream>>>(W1, B1p, F_IN, H1, 45, 224);
        convert_B<<<(int)((B2n + 255) / 256), 256, 0, stream>>>(W2, B2p, H1, H2, 7, 80);

        // ---- CSR build ----
        hipMemsetAsync(counts, 0, (size_t)N * sizeof(int), stream);
        hist_dst<<<2048, 256, 0, stream>>>(edge_dst, counts, E);
        chunk_sums<<<NB, 256, 0, stream>>>(counts, csum, N);
        scan_final<<<NB, 256, 0, stream>>>(counts, csum, row_start, cursor, N);
        scatter_edges<<<2048, 256, 0, stream>>>(edge_src, edge_dst, edge_w, cursor, csr, E);

        // ---- Layer 1 ----
        gemm_mfma_bstage<F_IN, 45, 224, 4, 2, 2, 7, false><<<MB, 512, 0, stream>>>(x, B1p, nullptr, h0, N, H1);
        {
            constexpr int G1 = 256 / (H1 / 4);   // 5 rows/block
            spmm_csr<H1, true><<<(N + G1 - 1) / G1, 256, 0, stream>>>(h0, csr, row_start, counts, b1, h1, N);
        }

        // ---- Layer 2 ----
        gemm_mfma_bstage<H1, 7, 80, 8, 1, 1, 5, false><<<MB, 512, 0, stream>>>(h1, B2p, nullptr, h2, N, H2);

        // ---- Layer-2 SPMM + fused FC ----
        {
            constexpr int G2 = 256 / (H2 / 4);   // 12 rows/block
            spmm_fc<H2, NC><<<(N + G2 - 1) / G2, 256, 0, stream>>>(h2, csr, row_start, counts, b2, Wfc, bfc, out, N);
        }
    } else {
        // ---- fallback: fp32 everything, atomic SPMM ----
        const int tilesM = (N + 63) / 64;
        gemm_tiled<<<tilesM * 4, 256, 0, stream>>>(x, W1, nullptr, h0, N, F_IN, H1, 4);
        init_bias_kernel<<<2048, 256, 0, stream>>>(agg, b1, (long long)N * H1, H1);
        spmm_edges<H1><<<(E + 3) / 4, 256, 0, stream>>>(h0, edge_src, edge_dst, edge_w, agg, E);
        relu_kernel<<<2048, 256, 0, stream>>>(agg, (long long)N * H1);
        gemm_tiled<<<tilesM * 2, 256, 0, stream>>>(h1, W2, nullptr, h2, N, H1, H2, 2);
        init_bias_kernel<<<2048, 256, 0, stream>>>(agg, b2, (long long)N * H2, H2);
        spmm_edges<H2><<<(E + 3) / 4, 256, 0, stream>>>(h2, edge_src, edge_dst, edge_w, agg, E);
        relu_kernel<<<2048, 256, 0, stream>>>(agg, (long long)N * H2);
        gemm_tiled<<<tilesM, 256, 0, stream>>>(agg, Wfc, bfc, out, N, H2, NC, 1);
    }
}